// Round 17
// baseline (78.348 us; speedup 1.0000x reference)
//
#include <hip/hip_runtime.h>

#define BATCH 128
#define C 64
#define L 4096
#define K 31

#define NT 512               // 8 waves
#define NWAVE 8
#define NWT 4                // wave-tiles per block
#define CH 32                // channels per half
#define RW 8                 // outputs per lane
#define WTILE 512
#define BTILE 2048           // block tile (4 wave-tiles); grid (2,128)=256 blocks

typedef float floatx4 __attribute__((ext_vector_type(4)));

__device__ __forceinline__ floatx4 ld4(const float* p) {
    return *reinterpret_cast<const floatx4*>(p);
}

// Fused: out[b,o,l] = S[b,l] for all o.
// Wave (wt=wv>>1, half=wv&1) scatters its 32 channels over its 512-output
// wave-tile into P[38] (literal indices). Cross-block scatter closed by
// ghost-sample accumulation on block-edge lanes. End: 2-hop exchange
// (neighbors wv+-2), half-reduce via rbuf, S->sbuf, 8-way broadcast store.
#define KSTEP(k) { const float wk = wp[k];                              \
    P[(k)+0] += wk * o0.x; P[(k)+1] += wk * o0.y;                       \
    P[(k)+2] += wk * o0.z; P[(k)+3] += wk * o0.w;                       \
    P[(k)+4] += wk * o1.x; P[(k)+5] += wk * o1.y;                       \
    P[(k)+6] += wk * o1.z; P[(k)+7] += wk * o1.w; }

__global__ __launch_bounds__(NT, 2)
void revconv_fused(const float* __restrict__ x,
                   const float* __restrict__ w,
                   float* __restrict__ out) {
    __shared__ float exL1[NWAVE][8];   // lane63's P[23..30]
    __shared__ float exL2a[NWAVE][8];  // lane62's P[31..37]
    __shared__ float exL2b[NWAVE][8];  // lane63's P[31..37]
    __shared__ float exR1[NWAVE][8];   // lane0's  P[7..14]
    __shared__ float exR2a[NWAVE][8];  // lane1's  P[0..6]
    __shared__ float exR2b[NWAVE][8];  // lane0's  P[0..6]
    __shared__ __align__(16) float rbuf[BTILE];
    __shared__ __align__(16) float sbuf[BTILE];

    const int tid  = threadIdx.x;
    const int wv   = tid >> 6;
    const int lane = tid & 63;
    const int wt   = wv >> 1;          // wave-tile 0..3 (pairs on SIMDs 2i,2i+1)
    const int half = wv & 1;           // channel half
    const int tile = blockIdx.x;       // 0..1
    const int b    = blockIdx.y;       // 0..127
    const int T0   = tile * BTILE;
    const int l0   = T0 + wt * WTILE + lane * RW;
    const int i0   = half * CH;
    const float* xb = x + (long)b * C * L;

    float P[38] = {};   // P[j] <-> output l0 - 15 + j

    const float* xi = xb + (long)i0 * L + l0;
    floatx4 o0 = ld4(xi), o1 = ld4(xi + 4);

    for (int c = 0; c < CH; ++c) {
        floatx4 n0 = o0, n1 = o1;
        if (c + 1 < CH) { n0 = ld4(xi + L); n1 = ld4(xi + L + 4); }

        const float* wp = w + (i0 + c) * K;   // wave-uniform -> s_load
        KSTEP(0)  KSTEP(1)  KSTEP(2)  KSTEP(3)  KSTEP(4)  KSTEP(5)
        KSTEP(6)  KSTEP(7)  KSTEP(8)  KSTEP(9)  KSTEP(10) KSTEP(11)
        KSTEP(12) KSTEP(13) KSTEP(14) KSTEP(15) KSTEP(16) KSTEP(17)
        KSTEP(18) KSTEP(19) KSTEP(20) KSTEP(21) KSTEP(22) KSTEP(23)
        KSTEP(24) KSTEP(25) KSTEP(26) KSTEP(27) KSTEP(28) KSTEP(29)
        KSTEP(30)

        o0 = n0; o1 = n1;
        xi += L;
    }

    // ---- block-edge ghost samples (sample p -> output l = p + k - 15) ----
    // Left ghosts p = T0-16+j (j=1..15): in-block taps k = 31-j..30,
    // target P[j+k-16] on lane 0 of wt==0. Only when T0 > 0.
    if (wt == 0 && lane == 0 && tile > 0) {
        for (int c = 0; c < CH; ++c) {
            const float* gp = xb + (long)(i0 + c) * L + T0 - 16;
            float g[16];
#pragma unroll
            for (int q = 0; q < 4; ++q)
                *reinterpret_cast<floatx4*>(&g[q * 4]) = ld4(gp + q * 4);
            const float* wp = w + (i0 + c) * K;
#pragma unroll
            for (int j = 1; j < 16; ++j)
#pragma unroll
                for (int k = 31 - j; k < 31; ++k)
                    P[j + k - 16] += wp[k] * g[j];
        }
    }
    // Right ghosts p = Tend+j (j=0..14): in-block taps k = 0..14-j,
    // target P[j+k+8] on lane 63 of wt==3. Only when Tend < L (tile==0).
    if (wt == NWT - 1 && lane == 63 && tile == 0) {
        for (int c = 0; c < CH; ++c) {
            const float* gp = xb + (long)(i0 + c) * L + T0 + BTILE;
            float g[16];
#pragma unroll
            for (int q = 0; q < 4; ++q)
                *reinterpret_cast<floatx4*>(&g[q * 4]) = ld4(gp + q * 4);
            const float* wp = w + (i0 + c) * K;
#pragma unroll
            for (int j = 0; j < 15; ++j)
#pragma unroll
                for (int k = 0; k <= 14 - j; ++k)
                    P[j + k + 8] += wp[k] * g[j];
        }
    }

    // ---- wave-tile edge partials to LDS ----
    if (lane == 63) {
#pragma unroll
        for (int j = 0; j < 8; ++j) exL1[wv][j] = P[23 + j];
#pragma unroll
        for (int j = 0; j < 7; ++j) exL2b[wv][j] = P[31 + j];
    }
    if (lane == 62) {
#pragma unroll
        for (int j = 0; j < 7; ++j) exL2a[wv][j] = P[31 + j];
    }
    if (lane == 0) {
#pragma unroll
        for (int j = 0; j < 8; ++j) exR1[wv][j] = P[7 + j];
#pragma unroll
        for (int j = 0; j < 7; ++j) exR2b[wv][j] = P[j];
    }
    if (lane == 1) {
#pragma unroll
        for (int j = 0; j < 7; ++j) exR2a[wv][j] = P[j];
    }
    __syncthreads();

    float res[RW];
#pragma unroll
    for (int r = 0; r < RW; ++r) res[r] = P[15 + r];

    // up1: lane-1's P[23+r]  (wave-tile edge via LDS, neighbor wv-2; block edge -> 0)
#pragma unroll
    for (int r = 0; r < 8; ++r) {
        float v = __shfl_up(P[23 + r], 1, 64);
        if (lane == 0) v = (wt > 0) ? exL1[wv - 2][r] : 0.f;
        res[r] += v;
    }
    // up2: lane-2's P[31+r], r=0..6
#pragma unroll
    for (int r = 0; r < 7; ++r) {
        float v = __shfl_up(P[31 + r], 2, 64);
        if (lane == 0)      v = (wt > 0) ? exL2a[wv - 2][r] : 0.f;
        else if (lane == 1) v = (wt > 0) ? exL2b[wv - 2][r] : 0.f;
        res[r] += v;
    }
    // down1: lane+1's P[7+r]
#pragma unroll
    for (int r = 0; r < 8; ++r) {
        float v = __shfl_down(P[7 + r], 1, 64);
        if (lane == 63) v = (wt < NWT - 1) ? exR1[wv + 2][r] : 0.f;
        res[r] += v;
    }
    // down2: lane+2's P[r-1], r=1..7
#pragma unroll
    for (int r = 1; r < 8; ++r) {
        float v = __shfl_down(P[r - 1], 2, 64);
        if (lane == 63)      v = (wt < NWT - 1) ? exR2a[wv + 2][r - 1] : 0.f;
        else if (lane == 62) v = (wt < NWT - 1) ? exR2b[wv + 2][r - 1] : 0.f;
        res[r] += v;
    }

    // ---- half reduction: odd half writes res, even half sums -> sbuf ----
    const int toff = wt * WTILE + lane * RW;
    if (half == 1) {
        floatx4 a0, a1;
        a0.x = res[0]; a0.y = res[1]; a0.z = res[2]; a0.w = res[3];
        a1.x = res[4]; a1.y = res[5]; a1.z = res[6]; a1.w = res[7];
        *reinterpret_cast<floatx4*>(&rbuf[toff])     = a0;
        *reinterpret_cast<floatx4*>(&rbuf[toff + 4]) = a1;
    }
    __syncthreads();
    if (half == 0) {
        floatx4 s0, s1;
        s0.x = res[0] + rbuf[toff];     s0.y = res[1] + rbuf[toff + 1];
        s0.z = res[2] + rbuf[toff + 2]; s0.w = res[3] + rbuf[toff + 3];
        s1.x = res[4] + rbuf[toff + 4]; s1.y = res[5] + rbuf[toff + 5];
        s1.z = res[6] + rbuf[toff + 6]; s1.w = res[7] + rbuf[toff + 7];
        *reinterpret_cast<floatx4*>(&sbuf[toff])     = s0;
        *reinterpret_cast<floatx4*>(&sbuf[toff + 4]) = s1;
    }
    __syncthreads();

    // ---- broadcast store: wave wv -> channels [8wv, 8wv+8) ----
    float* ob = out + ((long)b * C + wv * 8) * L + T0;
#pragma unroll
    for (int o = 0; o < 8; ++o) {
        float* op = ob + (long)o * L;
#pragma unroll
        for (int q = 0; q < 8; ++q) {
            const int idx4 = lane + q * 64;          // float4 index in tile
            const floatx4 v = ld4(&sbuf[idx4 * 4]);
            __builtin_nontemporal_store(v, reinterpret_cast<floatx4*>(op + idx4 * 4));
        }
    }
}

extern "C" void kernel_launch(void* const* d_in, const int* in_sizes, int n_in,
                              void* d_out, int out_size, void* d_ws, size_t ws_size,
                              hipStream_t stream) {
    const float* x = (const float*)d_in[0];   // [B, C, L] fp32
    const float* w = (const float*)d_in[1];   // [C, C, K] fp32; o=0 slice used
    float* out = (float*)d_out;               // [B, C, L] fp32

    dim3 grid(L / BTILE, BATCH);              // (2, 128) = 256 blocks
    revconv_fused<<<grid, NT, 0, stream>>>(x, w, out);
}